// Round 1
// baseline (321.225 us; speedup 1.0000x reference)
//
#include <hip/hip_runtime.h>
#include <hip/hip_bf16.h>

#define N_NODES   262144
#define BATCHES   4096
#define G_SLOTS   8
#define D_OUT     7
#define NODE_DIM  128
#define GLOB_DIM  128
#define HIDDEN    64
#define NEG_VAL   (-1000000000.0f)

// Stage 1: one wave per batch. Binary-search segment bounds in sorted batch[],
// then ballot-scan sel[] to find first G_SLOTS selected node indices.
__global__ void find_slots_kernel(const int* __restrict__ sel,
                                  const int* __restrict__ batch,
                                  int* __restrict__ slot_node,
                                  int N, int B) {
    int wave = (int)((blockIdx.x * blockDim.x + threadIdx.x) >> 6);
    int lane = (int)(threadIdx.x & 63);
    if (wave >= B) return;
    int b = wave;

    // lower_bound(b): first i with batch[i] >= b   (uniform across wave)
    int lo = 0, hi = N;
    while (lo < hi) { int mid = (lo + hi) >> 1; if (batch[mid] < b) lo = mid + 1; else hi = mid; }
    int start = lo;
    // lower_bound(b+1)
    hi = N;
    while (lo < hi) { int mid = (lo + hi) >> 1; if (batch[mid] < b + 1) lo = mid + 1; else hi = mid; }
    int end = lo;

    int found = 0;
    for (int base = start; base < end && found < G_SLOTS; base += 64) {
        int i = base + lane;
        bool s = (i < end) && (sel[i] != 0);
        unsigned long long m = __ballot(s);
        if (s) {
            int rank = found + __popcll(m & ((1ull << lane) - 1ull));
            if (rank < G_SLOTS) slot_node[b * G_SLOTS + rank] = i;
        }
        found += __popcll(m);
    }
    int f = found < G_SLOTS ? found : G_SLOTS;
    if (lane < G_SLOTS - f) slot_node[b * G_SLOTS + f + lane] = -1;
}

// Stage 2: one wave per (b,g) slot. Lane t computes h[t]; shuffle-reduce h@W2.
__global__ void mlp_kernel(const float* __restrict__ node,
                           const float* __restrict__ glob,
                           const int* __restrict__ slot_node,
                           const int* __restrict__ mmask,
                           const float* __restrict__ W1,
                           const float* __restrict__ b1,
                           const float* __restrict__ W2,
                           const float* __restrict__ b2,
                           float* __restrict__ out, int B) {
    int wave_in_block = (int)(threadIdx.x >> 6);
    int lane = (int)(threadIdx.x & 63);
    int slot = (int)blockIdx.x * (int)(blockDim.x >> 6) + wave_in_block;
    int total = B * G_SLOTS;
    if (slot >= total) return;
    int b = slot >> 3;          // /G_SLOTS
    int g = slot & 7;           // %G_SLOTS
    int nidx = slot_node[slot];

    float h = 0.0f;
    if (nidx >= 0) {
        const float* nrow = node + (size_t)nidx * NODE_DIM;
        const float* grow = glob + (size_t)b * GLOB_DIM;
        float acc = b1[lane];
#pragma unroll 8
        for (int k = 0; k < NODE_DIM; k++) {
            acc = fmaf(nrow[k], W1[k * HIDDEN + lane], acc);
        }
#pragma unroll 8
        for (int k = 0; k < GLOB_DIM; k++) {
            acc = fmaf(grow[k], W1[(NODE_DIM + k) * HIDDEN + lane], acc);
        }
        h = fmaxf(acc, 0.0f);
    }

    // out[d] = sum_t h[t] * W2[t*D_OUT + d] + b2[d]
    float p[D_OUT];
#pragma unroll
    for (int d = 0; d < D_OUT; d++) p[d] = h * W2[lane * D_OUT + d];
#pragma unroll
    for (int off = 32; off > 0; off >>= 1) {
#pragma unroll
        for (int d = 0; d < D_OUT; d++) p[d] += __shfl_down(p[d], off);
    }

    if (lane == 0) {
        int obase = slot * D_OUT;
#pragma unroll
        for (int d = 0; d < D_OUT; d++) {
            float v = (nidx >= 0) ? (p[d] + b2[d]) : NEG_VAL;
            bool mk = mmask[obase + d] != 0;
            out[obase + d] = mk ? v : NEG_VAL;
        }
    }
}

extern "C" void kernel_launch(void* const* d_in, const int* in_sizes, int n_in,
                              void* d_out, int out_size, void* d_ws, size_t ws_size,
                              hipStream_t stream) {
    const float* node  = (const float*)d_in[0];   // (N, 128)
    const float* glob  = (const float*)d_in[1];   // (B, 128)
    const int*   sel   = (const int*)d_in[2];     // (N,) bool->int
    const int*   batch = (const int*)d_in[3];     // (N,)
    const int*   mmask = (const int*)d_in[4];     // (B, G, D) bool->int
    const float* W1    = (const float*)d_in[5];   // (256, 64)
    const float* b1    = (const float*)d_in[6];   // (64,)
    const float* W2    = (const float*)d_in[7];   // (64, 7)
    const float* b2    = (const float*)d_in[8];   // (7,)
    float* out = (float*)d_out;

    int N = in_sizes[3];
    int B = in_sizes[1] / GLOB_DIM;

    int* slot_node = (int*)d_ws;                  // B*G ints

    // Stage 1: one wave per batch
    {
        int waves = B;
        int threads = 256;
        int blocks = (waves * 64 + threads - 1) / threads;
        find_slots_kernel<<<blocks, threads, 0, stream>>>(sel, batch, slot_node, N, B);
    }
    // Stage 2: one wave per slot
    {
        int waves = B * G_SLOTS;
        int threads = 256;
        int blocks = (waves * 64 + threads - 1) / threads;
        mlp_kernel<<<blocks, threads, 0, stream>>>(node, glob, slot_node, mmask,
                                                   W1, b1, W2, b2, out, B);
    }
}

// Round 2
// 205.987 us; speedup vs baseline: 1.5594x; 1.5594x over previous
//
#include <hip/hip_runtime.h>
#include <hip/hip_bf16.h>

#define G_SLOTS   8
#define D_OUT     7
#define NODE_DIM  128
#define GLOB_DIM  128
#define HIDDEN    64
#define NEG_VAL   (-1000000000.0f)

// ---------------- K1: segment starts from sorted batch[] --------------------
// starts[b] = first index i with batch[i] >= b, for b in [0, B]; starts[B] = N.
__global__ void seg_starts_kernel(const int* __restrict__ batch,
                                  int* __restrict__ starts, int N, int B) {
    int i = blockIdx.x * blockDim.x + threadIdx.x;
    if (i >= N) return;
    int b = batch[i];
    if (i == 0) {
        for (int bb = 0; bb <= b; ++bb) starts[bb] = 0;
    } else {
        int pb = batch[i - 1];
        for (int bb = pb + 1; bb <= b; ++bb) starts[bb] = i;
    }
    if (i == N - 1) {
        for (int bb = b + 1; bb <= B; ++bb) starts[bb] = N;
    }
}

// ---------------- K2: first G selected nodes per batch ----------------------
__global__ void find_slots_kernel(const int* __restrict__ sel,
                                  const int* __restrict__ starts,
                                  int* __restrict__ slot_node, int B) {
    int wave = (int)((blockIdx.x * blockDim.x + threadIdx.x) >> 6);
    int lane = (int)(threadIdx.x & 63);
    if (wave >= B) return;
    int b = wave;
    int start = starts[b], end = starts[b + 1];

    int found = 0;
    for (int base = start; base < end && found < G_SLOTS; base += 64) {
        int i = base + lane;
        bool s = (i < end) && (sel[i] != 0);
        unsigned long long m = __ballot(s);
        if (s) {
            int rank = found + __popcll(m & ((1ull << lane) - 1ull));
            if (rank < G_SLOTS) slot_node[b * G_SLOTS + rank] = i;
        }
        found += __popcll(m);
    }
    int f = found < G_SLOTS ? found : G_SLOTS;
    if (lane < G_SLOTS - f) slot_node[b * G_SLOTS + f + lane] = -1;
}

// ---------------- K3: gh[b][h] = b1[h] + glob[b] @ W1[128:,:] ---------------
// 256 threads = 4 waves; wave w handles batch blockIdx*4+w, lane = h.
__global__ void glob_mlp_kernel(const float* __restrict__ glob,
                                const float* __restrict__ W1,
                                const float* __restrict__ b1,
                                float* __restrict__ gh, int B) {
    __shared__ float w1g[GLOB_DIM * HIDDEN];   // 32 KB
    __shared__ float globl[4 * GLOB_DIM];      // 2 KB

    int t = threadIdx.x;
    int b0 = blockIdx.x * 4;
    // stage W1 glob part: floats [8192, 16384)
#pragma unroll
    for (int it = 0; it < 8; ++it) {
        int idx = it * 256 + t;  // float4 index
        *(float4*)&w1g[idx * 4] = *(const float4*)&W1[NODE_DIM * HIDDEN + idx * 4];
    }
    // stage 4 glob rows
    if (t < 128) {
        *(float4*)&globl[t * 4] = *(const float4*)&glob[(size_t)b0 * GLOB_DIM + t * 4];
    }
    __syncthreads();

    int w = t >> 6, lane = t & 63;
    float acc = b1[lane];
#pragma unroll 8
    for (int k = 0; k < GLOB_DIM; ++k) {
        acc = fmaf(globl[w * GLOB_DIM + k], w1g[k * HIDDEN + lane], acc);
    }
    gh[(size_t)(b0 + w) * HIDDEN + lane] = acc;
}

// ---------------- K4: node MLP + W2 + mask ----------------------------------
// Block: 256 threads, 64 slots (= 8 batches). Thread t: sl = t&63, part = t>>6
// owns hidden [part*16, part*16+16) of slot sl.
#define XSTRIDE 129
__global__ __launch_bounds__(256) void node_mlp_kernel(
        const float* __restrict__ node,
        const int* __restrict__ slot_node,
        const int* __restrict__ mmask,
        const float* __restrict__ W1,
        const float* __restrict__ W2,
        const float* __restrict__ b2,
        const float* __restrict__ gh,
        float* __restrict__ out) {
    __shared__ float w1n[NODE_DIM * HIDDEN];     // 32 KB
    __shared__ float xlds[64 * XSTRIDE];         // 33 KB, pad to kill conflicts
    __shared__ float w2l[HIDDEN * D_OUT];        // 1.75 KB
    __shared__ float b2l[D_OUT];
    __shared__ float pout[4 * 64 * D_OUT];       // 7 KB
    __shared__ int   nidxl[64];

    int t = threadIdx.x;
    int slot0 = blockIdx.x * 64;

    if (t < 64) nidxl[t] = slot_node[slot0 + t];
    // stage W1 node part: floats [0, 8192)
#pragma unroll
    for (int it = 0; it < 8; ++it) {
        int idx = it * 256 + t;
        *(float4*)&w1n[idx * 4] = *(const float4*)&W1[idx * 4];
    }
    if (t < 112) {
        *(float4*)&w2l[t * 4] = *(const float4*)&W2[t * 4];
    }
    if (t < D_OUT) b2l[t] = b2[t];
    __syncthreads();

    // stage 64 node rows: 4 threads per row, 32 floats each
    {
        int r = t >> 2, q = t & 3;
        int nidx = nidxl[r];
        int cbase = q * 32;
        if (nidx >= 0) {
            const float* src = node + (size_t)nidx * NODE_DIM + cbase;
#pragma unroll
            for (int j = 0; j < 8; ++j) {
                float4 v = *(const float4*)&src[j * 4];
                xlds[r * XSTRIDE + cbase + j * 4 + 0] = v.x;
                xlds[r * XSTRIDE + cbase + j * 4 + 1] = v.y;
                xlds[r * XSTRIDE + cbase + j * 4 + 2] = v.z;
                xlds[r * XSTRIDE + cbase + j * 4 + 3] = v.w;
            }
        } else {
#pragma unroll
            for (int j = 0; j < 32; ++j) xlds[r * XSTRIDE + cbase + j] = 0.0f;
        }
    }
    __syncthreads();

    int sl = t & 63, part = t >> 6;
    int slot = slot0 + sl;
    int b = slot >> 3;
    int hbase = part * 16;

    // init acc from gh (b1 + glob part already folded in)
    float acc[16];
#pragma unroll
    for (int j = 0; j < 4; ++j) {
        float4 v = *(const float4*)&gh[(size_t)b * HIDDEN + hbase + j * 4];
        acc[j * 4 + 0] = v.x; acc[j * 4 + 1] = v.y;
        acc[j * 4 + 2] = v.z; acc[j * 4 + 3] = v.w;
    }

#pragma unroll 4
    for (int k = 0; k < NODE_DIM; ++k) {
        float xk = xlds[sl * XSTRIDE + k];                 // conflict-free
        const float* wrow = &w1n[k * HIDDEN + hbase];      // wave-uniform: broadcast
#pragma unroll
        for (int hh = 0; hh < 16; ++hh) {
            acc[hh] = fmaf(xk, wrow[hh], acc[hh]);
        }
    }

    // relu + partial second layer
    float p[D_OUT];
#pragma unroll
    for (int d = 0; d < D_OUT; ++d) p[d] = (part == 0) ? b2l[d] : 0.0f;
#pragma unroll
    for (int hh = 0; hh < 16; ++hh) {
        float h = fmaxf(acc[hh], 0.0f);
        const float* w2row = &w2l[(hbase + hh) * D_OUT];   // wave-uniform: broadcast
#pragma unroll
        for (int d = 0; d < D_OUT; ++d) p[d] = fmaf(h, w2row[d], p[d]);
    }
#pragma unroll
    for (int d = 0; d < D_OUT; ++d) pout[part * (64 * D_OUT) + sl * D_OUT + d] = p[d];
    __syncthreads();

    // final: wave 0 reduces 4 partials, applies mask, writes
    if (t < 64) {
        int nidx = nidxl[t];
        int obase = (slot0 + t) * D_OUT;
#pragma unroll
        for (int d = 0; d < D_OUT; ++d) {
            float v = pout[0 * 448 + t * D_OUT + d] + pout[1 * 448 + t * D_OUT + d]
                    + pout[2 * 448 + t * D_OUT + d] + pout[3 * 448 + t * D_OUT + d];
            bool mk = mmask[obase + d] != 0;
            out[obase + d] = (nidx >= 0 && mk) ? v : NEG_VAL;
        }
    }
}

extern "C" void kernel_launch(void* const* d_in, const int* in_sizes, int n_in,
                              void* d_out, int out_size, void* d_ws, size_t ws_size,
                              hipStream_t stream) {
    const float* node  = (const float*)d_in[0];   // (N, 128)
    const float* glob  = (const float*)d_in[1];   // (B, 128)
    const int*   sel   = (const int*)d_in[2];     // (N,)
    const int*   batch = (const int*)d_in[3];     // (N,)
    const int*   mmask = (const int*)d_in[4];     // (B, G, D)
    const float* W1    = (const float*)d_in[5];   // (256, 64)
    const float* b1    = (const float*)d_in[6];   // (64,)
    const float* W2    = (const float*)d_in[7];   // (64, 7)
    const float* b2    = (const float*)d_in[8];   // (7,)
    float* out = (float*)d_out;

    int N = in_sizes[3];
    int B = in_sizes[1] / GLOB_DIM;

    // workspace layout
    int*   slot_node = (int*)d_ws;                                  // B*G ints = 128 KB
    int*   starts    = (int*)((char*)d_ws + (size_t)B * G_SLOTS * 4); // B+1 ints
    float* gh        = (float*)((char*)d_ws + (size_t)B * G_SLOTS * 4 + (size_t)(B + 64) * 4);

    seg_starts_kernel<<<(N + 255) / 256, 256, 0, stream>>>(batch, starts, N, B);
    find_slots_kernel<<<(B * 64 + 255) / 256, 256, 0, stream>>>(sel, starts, slot_node, B);
    glob_mlp_kernel<<<B / 4, 256, 0, stream>>>(glob, W1, b1, gh, B);
    node_mlp_kernel<<<(B * G_SLOTS) / 64, 256, 0, stream>>>(
        node, slot_node, mmask, W1, W2, b2, gh, out);
}

// Round 4
// 204.845 us; speedup vs baseline: 1.5681x; 1.0056x over previous
//
#include <hip/hip_runtime.h>
#include <hip/hip_bf16.h>

#define G_SLOTS   8
#define D_OUT     7
#define NODE_DIM  128
#define GLOB_DIM  128
#define HIDDEN    64
#define NEG_VAL   (-1000000000.0f)
#define XSTRIDE   129   // odd stride => per-slot xk reads conflict-free
#define GH_STRIDE 68    // 68*4B = 272B, multiple of 16

// ---------------- K1: segment starts from sorted batch[] --------------------
// starts[b] = first index i with batch[i] >= b, for b in [0, B]; starts[B] = N.
__global__ void seg_starts_kernel(const int* __restrict__ batch,
                                  int* __restrict__ starts, int N, int B) {
    int i = blockIdx.x * blockDim.x + threadIdx.x;
    if (i >= N) return;
    int b = batch[i];
    if (i == 0) {
        for (int bb = 0; bb <= b; ++bb) starts[bb] = 0;
    } else {
        int pb = batch[i - 1];
        for (int bb = pb + 1; bb <= b; ++bb) starts[bb] = i;
    }
    if (i == N - 1) {
        for (int bb = b + 1; bb <= B; ++bb) starts[bb] = N;
    }
}

// ---------------- K2: fused slots + MLP --------------------------------------
// Block: 256 threads = 4 waves, owns 64 slots = 8 batches (b0 .. b0+7).
// LDS total: 32768 + 33024 + 2176 + 1792 + 28 + 36 + 256 = 70,080 B
//  (< 75,036 B which is empirically proven to launch on gfx950 — R2 node_mlp).
__global__ __launch_bounds__(256) void fused_mlp_kernel(
        const float* __restrict__ node,
        const float* __restrict__ glob,
        const int* __restrict__ sel,
        const int* __restrict__ starts,
        const int* __restrict__ mmask,
        const float* __restrict__ W1,
        const float* __restrict__ b1,
        const float* __restrict__ W2,
        const float* __restrict__ b2,
        float* __restrict__ out) {
    __shared__ __align__(16) float w1n[NODE_DIM * HIDDEN];     // 32768 B
    __shared__ __align__(16) float xlds[64 * XSTRIDE];         // 33024 B
    __shared__ __align__(16) float gh_l[G_SLOTS * GH_STRIDE];  // 2176 B
    __shared__ __align__(16) float w2l[HIDDEN * D_OUT];        // 1792 B
    __shared__ __align__(16) float b2l[D_OUT + 1];             // 32 B
    __shared__ __align__(16) int   starts_l[G_SLOTS + 1];      // 36 B
    __shared__ __align__(16) int   nidxl[64];                  // 256 B

    int t = threadIdx.x;
    int b0 = (int)blockIdx.x * 8;                  // first batch of this block
    int slot0 = (int)blockIdx.x * 64;

    // ---- phase A: stage W1-node/W2/b2/starts; compute gh (glob half) ----
#pragma unroll
    for (int it = 0; it < 8; ++it) {
        int idx = it * 256 + t;                    // float4 index into W1[0:8192)
        *(float4*)&w1n[idx * 4] = *(const float4*)&W1[idx * 4];
    }
    if (t < 112) *(float4*)&w2l[t * 4] = *(const float4*)&W2[t * 4];
    if (t < D_OUT) b2l[t] = b2[t];
    if (t < 9) starts_l[t] = starts[b0 + t];

    {   // thread t -> batch bb = t>>5, hidden pair h0 = (t&31)*2
        int bb = t >> 5;
        int h0 = (t & 31) * 2;
        const float* grow = glob + (size_t)(b0 + bb) * GLOB_DIM;
        float ax = b1[h0], ay = b1[h0 + 1];
#pragma unroll 8
        for (int k = 0; k < GLOB_DIM; ++k) {
            float g = grow[k];                     // broadcast across 32 lanes
            ax = fmaf(g, W1[(NODE_DIM + k) * HIDDEN + h0],     ax);
            ay = fmaf(g, W1[(NODE_DIM + k) * HIDDEN + h0 + 1], ay);
        }
        gh_l[bb * GH_STRIDE + h0]     = ax;
        gh_l[bb * GH_STRIDE + h0 + 1] = ay;
    }
    __syncthreads();

    // ---- phase B: wave w ballot-scans batches 2w, 2w+1 ----
    {
        int w = t >> 6, lane = t & 63;
        for (int bi = w * 2; bi < w * 2 + 2; ++bi) {
            int start = starts_l[bi], end = starts_l[bi + 1];
            int found = 0;
            for (int base = start; base < end && found < G_SLOTS; base += 64) {
                int i = base + lane;
                bool s = (i < end) && (sel[i] != 0);
                unsigned long long m = __ballot(s);
                if (s) {
                    int rank = found + __popcll(m & ((1ull << lane) - 1ull));
                    if (rank < G_SLOTS) nidxl[bi * G_SLOTS + rank] = i;
                }
                found += __popcll(m);
            }
            int f = found < G_SLOTS ? found : G_SLOTS;
            if (lane < G_SLOTS - f) nidxl[bi * G_SLOTS + f + lane] = -1;
        }
    }
    __syncthreads();

    // ---- phase C: gather node rows (4 threads per row, 32 floats each) ----
    {
        int r = t >> 2, q = t & 3;
        int nidx = nidxl[r];
        int cbase = q * 32;
        if (nidx >= 0) {
            const float* src = node + (size_t)nidx * NODE_DIM + cbase;
#pragma unroll
            for (int j = 0; j < 8; ++j) {
                float4 v = *(const float4*)&src[j * 4];
                xlds[r * XSTRIDE + cbase + j * 4 + 0] = v.x;
                xlds[r * XSTRIDE + cbase + j * 4 + 1] = v.y;
                xlds[r * XSTRIDE + cbase + j * 4 + 2] = v.z;
                xlds[r * XSTRIDE + cbase + j * 4 + 3] = v.w;
            }
        } else {
#pragma unroll
            for (int j = 0; j < 32; ++j) xlds[r * XSTRIDE + cbase + j] = 0.0f;
        }
    }
    __syncthreads();

    // ---- phase D: sl = t>>2 owns slot; part = t&3 owns hidden [part*16,+16) ----
    // Parts of one slot sit in adjacent lanes -> cross-part reduce via shfl_xor.
    {
        int sl = t >> 2, part = t & 3;
        int bl = sl >> 3;                          // batch within block
        int hbase = part * 16;

        float acc[16];
#pragma unroll
        for (int j = 0; j < 16; ++j) acc[j] = gh_l[bl * GH_STRIDE + hbase + j];

#pragma unroll 4
        for (int k = 0; k < NODE_DIM; ++k) {
            float xk = xlds[sl * XSTRIDE + k];     // 4 lanes same addr: broadcast
            float4 w0  = *(const float4*)&w1n[k * HIDDEN + hbase + 0];
            float4 w1v = *(const float4*)&w1n[k * HIDDEN + hbase + 4];
            float4 w2v = *(const float4*)&w1n[k * HIDDEN + hbase + 8];
            float4 w3v = *(const float4*)&w1n[k * HIDDEN + hbase + 12];
            acc[0]  = fmaf(xk, w0.x,  acc[0]);  acc[1]  = fmaf(xk, w0.y,  acc[1]);
            acc[2]  = fmaf(xk, w0.z,  acc[2]);  acc[3]  = fmaf(xk, w0.w,  acc[3]);
            acc[4]  = fmaf(xk, w1v.x, acc[4]);  acc[5]  = fmaf(xk, w1v.y, acc[5]);
            acc[6]  = fmaf(xk, w1v.z, acc[6]);  acc[7]  = fmaf(xk, w1v.w, acc[7]);
            acc[8]  = fmaf(xk, w2v.x, acc[8]);  acc[9]  = fmaf(xk, w2v.y, acc[9]);
            acc[10] = fmaf(xk, w2v.z, acc[10]); acc[11] = fmaf(xk, w2v.w, acc[11]);
            acc[12] = fmaf(xk, w3v.x, acc[12]); acc[13] = fmaf(xk, w3v.y, acc[13]);
            acc[14] = fmaf(xk, w3v.z, acc[14]); acc[15] = fmaf(xk, w3v.w, acc[15]);
        }

        float p[D_OUT];
#pragma unroll
        for (int d = 0; d < D_OUT; ++d) p[d] = (part == 0) ? b2l[d] : 0.0f;
#pragma unroll
        for (int hh = 0; hh < 16; ++hh) {
            float h = fmaxf(acc[hh], 0.0f);
            const float* w2row = &w2l[(hbase + hh) * D_OUT];
#pragma unroll
            for (int d = 0; d < D_OUT; ++d) p[d] = fmaf(h, w2row[d], p[d]);
        }
        // reduce across the 4 parts (lanes differing in bits 0..1)
#pragma unroll
        for (int d = 0; d < D_OUT; ++d) {
            p[d] += __shfl_xor(p[d], 1);
            p[d] += __shfl_xor(p[d], 2);
        }
        if (part == 0) {
            int nidx = nidxl[sl];
            int obase = (slot0 + sl) * D_OUT;
#pragma unroll
            for (int d = 0; d < D_OUT; ++d) {
                bool mk = mmask[obase + d] != 0;
                out[obase + d] = (nidx >= 0 && mk) ? p[d] : NEG_VAL;
            }
        }
    }
}

extern "C" void kernel_launch(void* const* d_in, const int* in_sizes, int n_in,
                              void* d_out, int out_size, void* d_ws, size_t ws_size,
                              hipStream_t stream) {
    const float* node  = (const float*)d_in[0];   // (N, 128)
    const float* glob  = (const float*)d_in[1];   // (B, 128)
    const int*   sel   = (const int*)d_in[2];     // (N,)
    const int*   batch = (const int*)d_in[3];     // (N,)
    const int*   mmask = (const int*)d_in[4];     // (B, G, D)
    const float* W1    = (const float*)d_in[5];   // (256, 64)
    const float* b1    = (const float*)d_in[6];   // (64,)
    const float* W2    = (const float*)d_in[7];   // (64, 7)
    const float* b2    = (const float*)d_in[8];   // (7,)
    float* out = (float*)d_out;

    int N = in_sizes[3];
    int B = in_sizes[1] / GLOB_DIM;

    int* starts = (int*)d_ws;                     // B+1 ints

    seg_starts_kernel<<<(N + 255) / 256, 256, 0, stream>>>(batch, starts, N, B);
    fused_mlp_kernel<<<(B * G_SLOTS) / 64, 256, 0, stream>>>(
        node, glob, sel, starts, mmask, W1, b1, W2, b2, out);
}

// Round 8
// 190.607 us; speedup vs baseline: 1.6853x; 1.0747x over previous
//
#include <hip/hip_runtime.h>
#include <hip/hip_bf16.h>

#define G_SLOTS   8
#define D_OUT     7
#define NODE_DIM  128
#define GLOB_DIM  128
#define HIDDEN    64
#define NEG_VAL   (-1000000000.0f)
#define ROW_H     272            // halves per row; 544 B => uniform 8-per-bank b128
#define H_STRIDE  68             // f32 dwords; H row stride
#define POUT_OFF  4352           // f32 dword offset of pout inside wt (after H's 64*68)

typedef _Float16 half8 __attribute__((ext_vector_type(8)));
typedef float    f32x4 __attribute__((ext_vector_type(4)));

// ---------------- K1: segment starts from sorted batch[] --------------------
__global__ void seg_starts_kernel(const int* __restrict__ batch,
                                  int* __restrict__ starts, int N, int B) {
    int i = blockIdx.x * blockDim.x + threadIdx.x;
    if (i >= N) return;
    int b = batch[i];
    if (i == 0) {
        for (int bb = 0; bb <= b; ++bb) starts[bb] = 0;
    } else {
        int pb = batch[i - 1];
        for (int bb = pb + 1; bb <= b; ++bb) starts[bb] = i;
    }
    if (i == N - 1) {
        for (int bb = b + 1; bb <= B; ++bb) starts[bb] = N;
    }
}

// ---------------- K2: fused slots + f16-MFMA MLP -----------------------------
// Block: 256 threads = 4 waves, 64 slots = 8 batches.
// xa: [64 m][256 k] f16 (node cols 0..127, glob cols 128..255), row = slot.
// wt: [64 n][256 k] f16 (W1 transposed).  C = X @ W1 via mfma_f32_16x16x32_f16.
// After MFMA (barrier), wt's space is reused: H (f32 [64][68]) at dw 0,
// pout (f32 [4][448]) at dw POUT_OFF — disjoint, both < 8704 dw capacity.
// NOTE: every per-element epilogue loop MUST block-stride by 256 — a plain
// `if (t < 448)` with 256 threads silently drops elements 256..447 (R3/R5-R7 bug).
__global__ __launch_bounds__(256) void fused_mlp_kernel(
        const float* __restrict__ node,
        const float* __restrict__ glob,
        const int* __restrict__ sel,
        const int* __restrict__ starts,
        const int* __restrict__ mmask,
        const float* __restrict__ W1,
        const float* __restrict__ b1,
        const float* __restrict__ W2,
        const float* __restrict__ b2,
        float* __restrict__ out) {
    __shared__ __align__(16) _Float16 xa[64 * ROW_H];   // 34816 B
    __shared__ __align__(16) _Float16 wt[64 * ROW_H];   // 34816 B
    __shared__ __align__(16) int starts_l[G_SLOTS + 1];
    __shared__ __align__(16) int nidxl[64];

    int t = threadIdx.x;
    int b0 = (int)blockIdx.x * 8;
    int slot0 = (int)blockIdx.x * 64;

    if (t < 9) starts_l[t] = starts[b0 + t];

    // ---- stage W1^T as f16: thread (n = t&63, ko8 = (t>>6)*8) ----
    {
        int n = t & 63, ko8 = (t >> 6) * 8;
#pragma unroll
        for (int it = 0; it < 8; ++it) {
            int k0 = it * 32 + ko8;
            half8 hv;
#pragma unroll
            for (int j = 0; j < 8; ++j) {
                hv[j] = (_Float16)W1[(k0 + j) * HIDDEN + n];
            }
            *(half8*)&wt[n * ROW_H + k0] = hv;
        }
    }

    // ---- stage glob into xa cols 128..255: thread (r = t>>2, q = t&3) ----
    {
        int r = t >> 2, q = t & 3;
        const float* gsrc = glob + (size_t)(b0 + (r >> 3)) * GLOB_DIM + q * 32;
        int dst = r * ROW_H + 128 + q * 32;
#pragma unroll
        for (int jj = 0; jj < 4; ++jj) {
            half8 hv;
#pragma unroll
            for (int j = 0; j < 8; ++j) {
                hv[j] = (_Float16)gsrc[jj * 8 + j];
            }
            *(half8*)&xa[dst + jj * 8] = hv;
        }
    }
    __syncthreads();

    // ---- ballot scan: wave w handles batches 2w, 2w+1 ----
    {
        int w = t >> 6, lane = t & 63;
        for (int bi = w * 2; bi < w * 2 + 2; ++bi) {
            int start = starts_l[bi], end = starts_l[bi + 1];
            int found = 0;
            for (int base = start; base < end && found < G_SLOTS; base += 64) {
                int i = base + lane;
                bool s = (i < end) && (sel[i] != 0);
                unsigned long long m = __ballot(s);
                if (s) {
                    int rank = found + __popcll(m & ((1ull << lane) - 1ull));
                    if (rank < G_SLOTS) nidxl[bi * G_SLOTS + rank] = i;
                }
                found += __popcll(m);
            }
            int f = found < G_SLOTS ? found : G_SLOTS;
            if (lane < G_SLOTS - f) nidxl[bi * G_SLOTS + f + lane] = -1;
        }
    }
    __syncthreads();

    // ---- gather node rows into xa cols 0..127 (f16) ----
    {
        int r = t >> 2, q = t & 3;
        int nidx = nidxl[r];
        int dst = r * ROW_H + q * 32;
        if (nidx >= 0) {
            const float* src = node + (size_t)nidx * NODE_DIM + q * 32;
#pragma unroll
            for (int jj = 0; jj < 4; ++jj) {
                half8 hv;
#pragma unroll
                for (int j = 0; j < 8; ++j) {
                    hv[j] = (_Float16)src[jj * 8 + j];
                }
                *(half8*)&xa[dst + jj * 8] = hv;
            }
        } else {
            half8 hz;
#pragma unroll
            for (int j = 0; j < 8; ++j) hz[j] = (_Float16)0.0f;
#pragma unroll
            for (int jj = 0; jj < 4; ++jj) *(half8*)&xa[dst + jj * 8] = hz;
        }
    }
    __syncthreads();

    // ---- MFMA: wave w owns n-tile w. A[m=lane&15][k=quad*8+j]; B likewise ----
    int w = t >> 6, lane = t & 63;
    int col = lane & 15, quad = lane >> 4;
    f32x4 acc0, acc1, acc2, acc3;
    acc0 = 0.0f; acc1 = 0.0f; acc2 = 0.0f; acc3 = 0.0f;
    {
        int nrow = w * 16 + col;
#pragma unroll
        for (int kt = 0; kt < 8; ++kt) {
            half8 bf = *(const half8*)&wt[nrow * ROW_H + kt * 32 + quad * 8];
            half8 a0 = *(const half8*)&xa[(0 * 16 + col) * ROW_H + kt * 32 + quad * 8];
            half8 a1 = *(const half8*)&xa[(1 * 16 + col) * ROW_H + kt * 32 + quad * 8];
            half8 a2 = *(const half8*)&xa[(2 * 16 + col) * ROW_H + kt * 32 + quad * 8];
            half8 a3 = *(const half8*)&xa[(3 * 16 + col) * ROW_H + kt * 32 + quad * 8];
            acc0 = __builtin_amdgcn_mfma_f32_16x16x32_f16(a0, bf, acc0, 0, 0, 0);
            acc1 = __builtin_amdgcn_mfma_f32_16x16x32_f16(a1, bf, acc1, 0, 0, 0);
            acc2 = __builtin_amdgcn_mfma_f32_16x16x32_f16(a2, bf, acc2, 0, 0, 0);
            acc3 = __builtin_amdgcn_mfma_f32_16x16x32_f16(a3, bf, acc3, 0, 0, 0);
        }
    }
    int nh = w * 16 + col;
    float b1v = b1[nh];
    __syncthreads();                  // all waves done reading xa/wt

    // ---- H = relu(C + b1) into wt-space as f32; C/D: col=lane&15, row=quad*4+reg ----
    {
        float* H = (float*)wt;
#pragma unroll
        for (int reg = 0; reg < 4; ++reg) {
            int m0 = quad * 4 + reg;
            H[(m0 +  0) * H_STRIDE + nh] = fmaxf(acc0[reg] + b1v, 0.0f);
            H[(m0 + 16) * H_STRIDE + nh] = fmaxf(acc1[reg] + b1v, 0.0f);
            H[(m0 + 32) * H_STRIDE + nh] = fmaxf(acc2[reg] + b1v, 0.0f);
            H[(m0 + 48) * H_STRIDE + nh] = fmaxf(acc3[reg] + b1v, 0.0f);
        }
    }
    __syncthreads();

    // ---- second layer: thread (sl = t&63) over hidden [partu*16, +16) ----
    {
        const float* H = (const float*)wt;
        float* pout = (float*)wt + POUT_OFF;           // disjoint from H region
        int sl = t & 63;
        int partu = t >> 6;                            // wave-uniform
        float p[D_OUT];
#pragma unroll
        for (int d = 0; d < D_OUT; ++d) p[d] = 0.0f;
#pragma unroll
        for (int jj = 0; jj < 4; ++jj) {
            float4 hq = *(const float4*)&H[sl * H_STRIDE + partu * 16 + jj * 4];
            float hv0 = hq.x, hv1 = hq.y, hv2 = hq.z, hv3 = hq.w;
            int n0 = partu * 16 + jj * 4;              // wave-uniform -> scalar loads
#pragma unroll
            for (int d = 0; d < D_OUT; ++d) {
                float s = fmaf(hv0, W2[(n0 + 0) * D_OUT + d], p[d]);
                s = fmaf(hv1, W2[(n0 + 1) * D_OUT + d], s);
                s = fmaf(hv2, W2[(n0 + 2) * D_OUT + d], s);
                s = fmaf(hv3, W2[(n0 + 3) * D_OUT + d], s);
                p[d] = s;
            }
        }
#pragma unroll
        for (int d = 0; d < D_OUT; ++d) pout[partu * 448 + sl * D_OUT + d] = p[d];
    }
    __syncthreads();

    // ---- final reduce + bias + mask + store: 448 elems, 256 threads ----
    // BLOCK-STRIDE, not `if (t < 448)` — that dropped elems 256..447 (R3/R5-R7).
    {
        const float* pout = (const float*)wt + POUT_OFF;
        for (int e = t; e < 64 * D_OUT; e += 256) {
            int sl = e / D_OUT, d = e - sl * D_OUT;
            float v = pout[e] + pout[448 + e] + pout[896 + e] + pout[1344 + e] + b2[d];
            int oidx = slot0 * D_OUT + e;
            bool ok = (nidxl[sl] >= 0) && (mmask[oidx] != 0);
            out[oidx] = ok ? v : NEG_VAL;
        }
    }
}

extern "C" void kernel_launch(void* const* d_in, const int* in_sizes, int n_in,
                              void* d_out, int out_size, void* d_ws, size_t ws_size,
                              hipStream_t stream) {
    const float* node  = (const float*)d_in[0];   // (N, 128)
    const float* glob  = (const float*)d_in[1];   // (B, 128)
    const int*   sel   = (const int*)d_in[2];     // (N,)
    const int*   batch = (const int*)d_in[3];     // (N,)
    const int*   mmask = (const int*)d_in[4];     // (B, G, D)
    const float* W1    = (const float*)d_in[5];   // (256, 64)
    const float* b1    = (const float*)d_in[6];   // (64,)
    const float* W2    = (const float*)d_in[7];   // (64, 7)
    const float* b2    = (const float*)d_in[8];   // (7,)
    float* out = (float*)d_out;

    int N = in_sizes[3];
    int B = in_sizes[1] / GLOB_DIM;

    int* starts = (int*)d_ws;                     // B+1 ints

    seg_starts_kernel<<<(N + 255) / 256, 256, 0, stream>>>(batch, starts, N, B);
    fused_mlp_kernel<<<(B * G_SLOTS) / 64, 256, 0, stream>>>(
        node, glob, sel, starts, mmask, W1, b1, W2, b2, out);
}